// Round 3
// baseline (154.978 us; speedup 1.0000x reference)
//
#include <hip/hip_runtime.h>

#define NCHAN 12
#define NBINS 2200
#define HMAX  (1000.0f)
#define SLICE_ELEMS 65536      // 256*256, one (batch, channel) slab
#define SPLIT 4                // blocks per slab -> 1536 blocks = 6/CU
#define BLOCK 256

__device__ __forceinline__ void bin4(const float4 v, unsigned int* lh) {
    float vals[4] = {v.x, v.y, v.z, v.w};
#pragma unroll
    for (int j = 0; j < 4; ++j) {
        // Bin width is exactly 1.0f (2200 bins over [-1200, 1000]), so
        // bin = floor(f + 1200).  For t >= 0, (int)t truncation == floor.
        // t >= 0.0f  <=>  f >= -1200.0f in fp32 (boundary rounding checked).
        // NaN fails t >= 0.  f == 1000 -> t = 2200 -> min -> last bin,
        // matching torch.histc.
        float t = vals[j] + 1200.0f;
        if (t >= 0.0f && vals[j] <= HMAX) {
            int idx = min((int)t, NBINS - 1);
            atomicAdd(&lh[idx], 1u);
        }
    }
}

// Stage 1: per-block private LDS histogram over one slab chunk, then a PLAIN
// coalesced store of all 2200 bins into the workspace (no global atomics —
// round-2 counters showed the atomic flush caused 128x write amplification
// from cross-XCD cacheline ping-pong).
__global__ __launch_bounds__(BLOCK)
void hist_kernel(const float* __restrict__ x, unsigned int* __restrict__ ws) {
    __shared__ unsigned int lh[NBINS];
    for (int i = threadIdx.x; i < NBINS; i += BLOCK) lh[i] = 0u;
    __syncthreads();

    const int slice = blockIdx.x / SPLIT;     // = b*NCHAN + c (layout [B,C,H,W])
    const int sub   = blockIdx.x % SPLIT;
    const int chunk = SLICE_ELEMS / SPLIT;    // 16384 elements per block

    const float4* __restrict__ xp =
        (const float4*)(x + (long long)slice * SLICE_ELEMS + (long long)sub * chunk);

    // chunk/4 = 4096 float4 = 2 outer iters x (256 threads x 8 loads).
    // Exact fit: 4096 == 2 * BLOCK * 8, so no bounds check needed.
#pragma unroll
    for (int k = 0; k < 2; ++k) {
        const int base = threadIdx.x + k * (BLOCK * 8);
        float4 v[8];
#pragma unroll
        for (int u = 0; u < 8; ++u) v[u] = xp[base + u * BLOCK];
#pragma unroll
        for (int u = 0; u < 8; ++u) bin4(v[u], lh);
    }
    __syncthreads();

    // Plain store of the full partial histogram (ws is poisoned each iter,
    // so zero bins must be written too). 9 coalesced stores per thread.
    unsigned int* __restrict__ wsb = ws + (long long)blockIdx.x * NBINS;
    for (int i = threadIdx.x; i < NBINS; i += BLOCK) wsb[i] = lh[i];
}

// Stage 2: out[c*NBINS+bin] = hist[c*NBINS+bin] + sum over all partials for
// channel c.  Partial p for (b, c, sub) lives at ws[((b*NCHAN+c)*SPLIT+sub)].
// Consecutive threads = consecutive bins -> every load is a coalesced 256 B
// segment.  Four independent accumulator chains for ILP.  Folds init_out.
__global__ __launch_bounds__(BLOCK)
void reduce_kernel(const unsigned int* __restrict__ ws,
                   const float* __restrict__ hist,
                   float* __restrict__ out, int nbatch) {
    int idx = blockIdx.x * BLOCK + threadIdx.x;
    if (idx >= NCHAN * NBINS) return;
    int c   = idx / NBINS;
    int bin = idx - c * NBINS;

    unsigned int s0 = 0, s1 = 0, s2 = 0, s3 = 0;
#pragma unroll 4
    for (int b = 0; b < nbatch; ++b) {
        const unsigned int* p =
            ws + (long long)((b * NCHAN + c) * SPLIT) * NBINS + bin;
        s0 += p[0 * NBINS];
        s1 += p[1 * NBINS];
        s2 += p[2 * NBINS];
        s3 += p[3 * NBINS];
    }
    // Counts are integer-valued and far below 2^24: exact in fp32.
    out[idx] = hist[idx] + (float)(s0 + s1 + s2 + s3);
}

extern "C" void kernel_launch(void* const* d_in, const int* in_sizes, int n_in,
                              void* d_out, int out_size, void* d_ws, size_t ws_size,
                              hipStream_t stream) {
    const float* x    = (const float*)d_in[0];
    const float* hist = (const float*)d_in[1];
    float* out        = (float*)d_out;
    unsigned int* ws  = (unsigned int*)d_ws;

    int nslices = in_sizes[0] / SLICE_ELEMS;          // 32*12 = 384
    int nbatch  = nslices / NCHAN;                    // 32

    // Stage 1: per-block partial histograms into workspace (13.5 MB).
    hist_kernel<<<nslices * SPLIT, BLOCK, 0, stream>>>(x, ws);

    // Stage 2: reduce partials + hist_counts -> out (also covers init).
    int total = NCHAN * NBINS;
    int nblk  = (total + BLOCK - 1) / BLOCK;
    reduce_kernel<<<nblk, BLOCK, 0, stream>>>(ws, hist, out, nbatch);
}

// Round 5
// 149.761 us; speedup vs baseline: 1.0348x; 1.0348x over previous
//
#include <hip/hip_runtime.h>

#define NCHAN 12
#define NBINS 2200
#define HMAX  (1000.0f)
#define SLICE_ELEMS 65536      // 256*256, one (batch, channel) slab
#define SPLIT 4                // blocks per slab -> 1536 blocks = 6/CU
#define BLOCK 256

// Kernel 1: out = hist_counts (WRITE, not add — d_out is poisoned 0xAA).
// float4-vectorized; scalar tail for generality.
__global__ __launch_bounds__(BLOCK)
void init_out(const float* __restrict__ hist, float* __restrict__ out, int n) {
    int i = (blockIdx.x * BLOCK + threadIdx.x) * 4;
    if (i + 3 < n) {
        *(float4*)(out + i) = *(const float4*)(hist + i);
    } else {
        for (; i < n; ++i) out[i] = hist[i];
    }
}

__device__ __forceinline__ void bin4(const float4 v, unsigned int* lh) {
    float vals[4] = {v.x, v.y, v.z, v.w};
#pragma unroll
    for (int j = 0; j < 4; ++j) {
        // Bin width is exactly 1.0f (2200 bins over [-1200, 1000]), so
        // bin = floor(f + 1200).  For t >= 0, (int)t truncation == floor.
        // t >= 0.0f  <=>  f >= -1200.0f in fp32 (boundary rounding checked).
        // NaN fails t >= 0.  f == 1000 -> t = 2200 -> min -> last bin,
        // matching torch.histc.
        float t = vals[j] + 1200.0f;
        if (t >= 0.0f && vals[j] <= HMAX) {
            int idx = min((int)t, NBINS - 1);
            atomicAdd(&lh[idx], 1u);
        }
    }
}

// Per-block private LDS histogram, then global float atomicAdd flush.
// (Round-2/3 structure — the only round-family that always passed; the
// two-stage ws variant is dropped after round-4's post-timing divergence.)
//
// KEY FIX this round: rounds 1-4 requested 8-16 loads in flight, but
// VGPR_Count=24 in the profiles proves the compiler re-interleaved the
// burst into load->bin->load->bin with ~3 live buffers — MLP never
// happened.  __builtin_amdgcn_sched_barrier(0) is a hard fence the
// scheduler cannot move instructions across: all 16 global_load_dwordx4
// must issue before any binning.  Latency math: 24 waves/CU x 16 loads
// = 384 outstanding float4/CU = 6 KB in flight ~= 10.3 B/cy x 600 cy.
__global__ __launch_bounds__(BLOCK)
void hist_kernel(const float* __restrict__ x, float* __restrict__ out) {
    __shared__ unsigned int lh[NBINS];
    for (int i = threadIdx.x; i < NBINS; i += BLOCK) lh[i] = 0u;
    __syncthreads();

    const int slice = blockIdx.x / SPLIT;     // = b*NCHAN + c (layout [B,C,H,W])
    const int sub   = blockIdx.x % SPLIT;
    const int c     = slice % NCHAN;
    const int chunk = SLICE_ELEMS / SPLIT;    // 16384 elements per block

    const float4* __restrict__ xp =
        (const float4*)(x + (long long)slice * SLICE_ELEMS + (long long)sub * chunk);

    // chunk/4 = 4096 float4 = 256 threads x 16.  Exact fit, no bounds check.
    float4 v[16];
#pragma unroll
    for (int u = 0; u < 16; ++u) v[u] = xp[threadIdx.x + u * BLOCK];
    // Fence: no binning instruction may be scheduled above this point, so
    // the 16 loads stay in flight together (VGPR ~80, still 6 blocks/CU).
    __builtin_amdgcn_sched_barrier(0);
#pragma unroll
    for (int u = 0; u < 16; ++u) bin4(v[u], lh);

    __syncthreads();

    float* __restrict__ outc = out + c * NBINS;
    for (int i = threadIdx.x; i < NBINS; i += BLOCK) {
        unsigned int cnt = lh[i];
        if (cnt) atomicAdd(&outc[i], (float)cnt);  // integer-valued, exact fp32
    }
}

extern "C" void kernel_launch(void* const* d_in, const int* in_sizes, int n_in,
                              void* d_out, int out_size, void* d_ws, size_t ws_size,
                              hipStream_t stream) {
    const float* x    = (const float*)d_in[0];
    const float* hist = (const float*)d_in[1];
    float* out        = (float*)d_out;

    // 1) out = hist_counts  (out_size = 26400 elements; float4 path)
    int nvec = (out_size + 3) / 4;
    int nblk = (nvec + BLOCK - 1) / BLOCK;
    init_out<<<nblk, BLOCK, 0, stream>>>(hist, out, out_size);

    // 2) accumulate batch histogram
    int nslices = in_sizes[0] / SLICE_ELEMS;          // 32*12 = 384
    hist_kernel<<<nslices * SPLIT, BLOCK, 0, stream>>>(x, out);
}